// Round 1
// baseline (255.018 us; speedup 1.0000x reference)
//
#include <hip/hip_runtime.h>
#include <math.h>

// Problem constants (from reference)
#define BB 64
#define TT 100
#define NN 20
#define NRR 380   // N*(N-1)

__global__ __launch_bounds__(256) void gp_kernel(
    const float* __restrict__ state,    // (B,T,N,8)
    const float* __restrict__ shape,    // (B,T,N,4)
    const float* __restrict__ relinfo,  // (B,T,NR,3)
    float* __restrict__ out)
{
    const int bt  = blockIdx.x;       // 0..B*T-1
    const int tid = threadIdx.x;

    __shared__ float s_state[NN * 8]; // 160 floats
    __shared__ float s_shape[NN * 4]; // 80 floats

    // ---- stage inputs for this (b,t) into LDS ----
    {
        const size_t stbase = (size_t)bt * NN * 8;
        const size_t shbase = (size_t)bt * NN * 4;
        if (tid < NN * 8)              s_state[tid]          = state[stbase + tid];
        else if (tid < NN * 8 + NN*4)  s_shape[tid - NN * 8] = shape[shbase + (tid - NN * 8)];
    }
    __syncthreads();

    const float  THRESH  = 0.35f;
    const float  HALF_PI = 1.57079632679489661923f; // float32(pi/2), matches jnp.asarray(math.pi/2, f32)

    const size_t REL_SZ = (size_t)BB * TT * NRR * 20;
    const size_t OBJ_SZ = (size_t)BB * TT * NN * 7;
    float* out_rel  = out;
    float* out_obj  = out + REL_SZ;
    float* out_recv = out + REL_SZ + OBJ_SZ;
    float* out_send = out + REL_SZ + OBJ_SZ + REL_SZ;

    // ---- per-object output (7 floats each) ----
    if (tid < NN) {
        const int n = tid;
        const float ang  = s_state[n * 8 + 2];
        const float c1 = cosf(ang),            s1 = sinf(ang);
        const float c2 = cosf(ang + HALF_PI),  s2 = sinf(ang + HALF_PI);
        const float vx = s_state[n * 8 + 3], vy = s_state[n * 8 + 4];
        float* o = out_obj + ((size_t)bt * NN + n) * 7;
        o[0] = c1 * vx + s1 * vy;
        o[1] = c2 * vx + s2 * vy;
        o[2] = s_state[n * 8 + 5];
        o[3] = s_shape[n * 4 + 0];
        o[4] = s_shape[n * 4 + 1];
        o[5] = s_shape[n * 4 + 2];
        o[6] = s_shape[n * 4 + 3];
    }

    // ---- per-pair outputs ----
    for (int r = tid; r < NRR; r += 256) {
        const int i = r / 19;
        const int l = r - i * 19;
        const int j = (l < i) ? l : (l + 1);

        const float* si = &s_state[i * 8];
        const float* sj = &s_state[j * 8];

        const float dx = si[0] - sj[0];
        const float dy = si[1] - sj[1];
        const float d  = sqrtf(dx * dx + dy * dy);
        const float mask = (d < THRESH && d > 0.0f) ? 1.0f : 0.0f;

        // diff_state = mask*(state_j - state_i)   (mask in {0,1} => exact vs reference)
        const float dpx   = mask * (sj[0] - si[0]);
        const float dpy   = mask * (sj[1] - si[1]);
        const float adiff = mask * (sj[2] - si[2]);
        const float dvx   = mask * (sj[3] - si[3]);
        const float dvy   = mask * (sj[4] - si[4]);
        const float advel = mask * (sj[5] - si[5]);
        const float ctlx  = mask * sj[6];
        const float ctly  = mask * sj[7];

        // receiver basis: angle = mask * state_i[2]  (recv_ang from masked receivers_state)
        const float rang = mask * si[2];
        const float c1 = cosf(rang),           s1 = sinf(rang);
        const float c2 = cosf(rang + HALF_PI), s2 = sinf(rang + HALF_PI);

        const float* ri = relinfo + ((size_t)bt * NRR + r) * 3;

        float4 w0, w1, w2, w3, w4;
        w0.x = ri[0];
        w0.y = ri[1];
        w0.z = ri[2];
        w0.w = c1 * dpx + s1 * dpy;           // diff_pos rotated, comp 0
        w1.x = c2 * dpx + s2 * dpy;           // comp 1
        w1.y = c1 * dvx + s1 * dvy;           // diff_vel rotated
        w1.z = c2 * dvx + s2 * dvy;
        w1.w = c1 * ctlx + s1 * ctly;         // control rotated
        w2.x = c2 * ctlx + s2 * ctly;
        w2.y = sinf(2.0f * adiff);            // diff_angle_2d
        w2.z = cosf(2.0f * adiff);            // == 1 when masked out, as in reference
        w2.w = advel;
        w3.x = mask * s_shape[i * 4 + 0];     // receivers_shape
        w3.y = mask * s_shape[i * 4 + 1];
        w3.z = mask * s_shape[i * 4 + 2];
        w3.w = mask * s_shape[i * 4 + 3];
        w4.x = mask * s_shape[j * 4 + 0];     // senders_shape
        w4.y = mask * s_shape[j * 4 + 1];
        w4.z = mask * s_shape[j * 4 + 2];
        w4.w = mask * s_shape[j * 4 + 3];

        float4* rd = (float4*)(out_rel + ((size_t)bt * NRR + r) * 20);
        rd[0] = w0; rd[1] = w1; rd[2] = w2; rd[3] = w3; rd[4] = w4;

        // receiver_relations row: mask at column i, zeros elsewhere
        float4* rv = (float4*)(out_recv + ((size_t)bt * NRR + r) * 20);
        float4* sv = (float4*)(out_send + ((size_t)bt * NRR + r) * 20);
#pragma unroll
        for (int q = 0; q < 5; ++q) {
            float4 v;
            v.x = (i == q * 4 + 0) ? mask : 0.0f;
            v.y = (i == q * 4 + 1) ? mask : 0.0f;
            v.z = (i == q * 4 + 2) ? mask : 0.0f;
            v.w = (i == q * 4 + 3) ? mask : 0.0f;
            rv[q] = v;
            float4 u;
            u.x = (j == q * 4 + 0) ? mask : 0.0f;
            u.y = (j == q * 4 + 1) ? mask : 0.0f;
            u.z = (j == q * 4 + 2) ? mask : 0.0f;
            u.w = (j == q * 4 + 3) ? mask : 0.0f;
            sv[q] = u;
        }
    }
}

extern "C" void kernel_launch(void* const* d_in, const int* in_sizes, int n_in,
                              void* d_out, int out_size, void* d_ws, size_t ws_size,
                              hipStream_t stream) {
    const float* state = (const float*)d_in[0];
    const float* shp   = (const float*)d_in[1];
    const float* rel   = (const float*)d_in[2];
    float* out = (float*)d_out;
    gp_kernel<<<dim3(BB * TT), dim3(256), 0, stream>>>(state, shp, rel, out);
}

// Round 2
// 168.170 us; speedup vs baseline: 1.5164x; 1.5164x over previous
//
#include <hip/hip_runtime.h>
#include <math.h>

// Problem constants (from reference)
#define BB 64
#define TT 100
#define NN 20
#define NRR 380   // N*(N-1)

__global__ __launch_bounds__(256) void gp_kernel(
    const float* __restrict__ state,    // (B,T,N,8)
    const float* __restrict__ shape,    // (B,T,N,4)
    const float* __restrict__ relinfo,  // (B,T,NR,3)
    float* __restrict__ out)
{
    const int bt  = blockIdx.x;       // 0..B*T-1
    const int tid = threadIdx.x;

    __shared__ float s_state[NN * 8]; // 160 floats
    __shared__ float s_shape[NN * 4]; // 80 floats

    // ---- stage inputs for this (b,t) into LDS ----
    if (tid < NN * 8)                   s_state[tid]          = state[(size_t)bt * NN * 8 + tid];
    else if (tid < NN * 8 + NN * 4)     s_shape[tid - NN * 8] = shape[(size_t)bt * NN * 4 + (tid - NN * 8)];
    __syncthreads();

    const float THRESH  = 0.35f;
    const float HALF_PI = 1.57079632679489661923f; // float32(pi/2)

    const size_t REL_SZ = (size_t)BB * TT * NRR * 20;
    const size_t OBJ_SZ = (size_t)BB * TT * NN * 7;
    float4* rel4    = (float4*)out;
    float*  out_obj = out + REL_SZ;
    float4* recv4   = (float4*)(out + REL_SZ + OBJ_SZ);
    float4* send4   = (float4*)(out + REL_SZ + OBJ_SZ + REL_SZ);

    // ---- obj_data: 140 consecutive floats per bt, coalesced scalar writes ----
    if (tid < NN * 7) {
        const int n = tid / 7;
        const int c = tid - n * 7;
        float v;
        if (c < 2) {
            const float ang = s_state[n * 8 + 2];
            const float a   = (c == 0) ? ang : (ang + HALF_PI);
            v = cosf(a) * s_state[n * 8 + 3] + sinf(a) * s_state[n * 8 + 4];
        } else if (c == 2) {
            v = s_state[n * 8 + 5];
        } else {
            v = s_shape[n * 4 + (c - 3)];
        }
        out_obj[(size_t)bt * NN * 7 + tid] = v;
    }

    // ---- pair outputs: 5 float4-quads per row; idx = r*5+q -> contiguous 16B stores ----
    for (int idx = tid; idx < NRR * 5; idx += 256) {
        const int r = idx / 5;
        const int q = idx - r * 5;
        const int i = r / 19;
        const int l = r - i * 19;
        const int j = (l < i) ? l : (l + 1);

        const float* si = &s_state[i * 8];
        const float* sj = &s_state[j * 8];

        const float dx = si[0] - sj[0];
        const float dy = si[1] - sj[1];
        const float d  = sqrtf(dx * dx + dy * dy);
        const float mask = (d < THRESH && d > 0.0f) ? 1.0f : 0.0f;

        // receiver basis (recv_ang = mask * state_i[2], matching masked receivers_state)
        const float rang = mask * si[2];
        const float c1 = cosf(rang),           s1 = sinf(rang);
        const float c2 = cosf(rang + HALF_PI), s2 = sinf(rang + HALF_PI);

        float4 w;
        if (q == 0) {
            const float* ri = relinfo + ((size_t)bt * NRR + r) * 3;
            const float dpx = mask * (sj[0] - si[0]);
            const float dpy = mask * (sj[1] - si[1]);
            w.x = ri[0]; w.y = ri[1]; w.z = ri[2];
            w.w = c1 * dpx + s1 * dpy;
        } else if (q == 1) {
            const float dpx = mask * (sj[0] - si[0]);
            const float dpy = mask * (sj[1] - si[1]);
            const float dvx = mask * (sj[3] - si[3]);
            const float dvy = mask * (sj[4] - si[4]);
            const float cx  = mask * sj[6], cy = mask * sj[7];
            w.x = c2 * dpx + s2 * dpy;
            w.y = c1 * dvx + s1 * dvy;
            w.z = c2 * dvx + s2 * dvy;
            w.w = c1 * cx  + s1 * cy;
        } else if (q == 2) {
            const float cx    = mask * sj[6], cy = mask * sj[7];
            const float adiff = mask * (sj[2] - si[2]);
            w.x = c2 * cx + s2 * cy;
            w.y = sinf(2.0f * adiff);
            w.z = cosf(2.0f * adiff);   // == 1 when masked out, as in reference
            w.w = mask * (sj[5] - si[5]);
        } else if (q == 3) {
            w.x = mask * s_shape[i * 4 + 0];
            w.y = mask * s_shape[i * 4 + 1];
            w.z = mask * s_shape[i * 4 + 2];
            w.w = mask * s_shape[i * 4 + 3];
        } else {
            w.x = mask * s_shape[j * 4 + 0];
            w.y = mask * s_shape[j * 4 + 1];
            w.z = mask * s_shape[j * 4 + 2];
            w.w = mask * s_shape[j * 4 + 3];
        }

        const size_t o = (size_t)bt * NRR * 5 + idx;
        rel4[o] = w;

        // one-hot relation rows: mask at column i (recv) / j (send)
        const int qb = q * 4;
        float4 rv, sv;
        rv.x = (i == qb + 0) ? mask : 0.0f;
        rv.y = (i == qb + 1) ? mask : 0.0f;
        rv.z = (i == qb + 2) ? mask : 0.0f;
        rv.w = (i == qb + 3) ? mask : 0.0f;
        sv.x = (j == qb + 0) ? mask : 0.0f;
        sv.y = (j == qb + 1) ? mask : 0.0f;
        sv.z = (j == qb + 2) ? mask : 0.0f;
        sv.w = (j == qb + 3) ? mask : 0.0f;
        recv4[o] = rv;
        send4[o] = sv;
    }
}

extern "C" void kernel_launch(void* const* d_in, const int* in_sizes, int n_in,
                              void* d_out, int out_size, void* d_ws, size_t ws_size,
                              hipStream_t stream) {
    const float* state = (const float*)d_in[0];
    const float* shp   = (const float*)d_in[1];
    const float* rel   = (const float*)d_in[2];
    float* out = (float*)d_out;
    gp_kernel<<<dim3(BB * TT), dim3(256), 0, stream>>>(state, shp, rel, out);
}

// Round 3
// 123.815 us; speedup vs baseline: 2.0597x; 1.3582x over previous
//
#include <hip/hip_runtime.h>
#include <math.h>

// Problem constants (from reference)
#define BB 64
#define TT 100
#define NN 20
#define NRR 380   // N*(N-1)

__global__ __launch_bounds__(256) void gp_kernel(
    const float* __restrict__ state,    // (B,T,N,8)
    const float* __restrict__ shape,    // (B,T,N,4)
    const float* __restrict__ relinfo,  // (B,T,NR,3)
    float* __restrict__ out)
{
    const int bt  = blockIdx.x;       // 0..B*T-1
    const int tid = threadIdx.x;

    __shared__ float  s_state[NN * 8];     // 160 floats
    __shared__ float  s_shape[NN * 4];     // 80 floats
    __shared__ float4 s_row4[NRR * 5];     // full rel_data rows, output-linear layout (30.4 KB)
    __shared__ float  s_mask[NRR];
    __shared__ int    s_ij[NRR];           // packed i | (j<<8)

    // ---- phase 0: stage state/shape for this (b,t) ----
    if (tid < NN * 8)                   s_state[tid]          = state[(size_t)bt * NN * 8 + tid];
    else if (tid < NN * 8 + NN * 4)     s_shape[tid - NN * 8] = shape[(size_t)bt * NN * 4 + (tid - NN * 8)];
    __syncthreads();

    const float THRESH  = 0.35f;
    const float HALF_PI = 1.57079632679489661923f; // float32(pi/2)

    const size_t REL_SZ = (size_t)BB * TT * NRR * 20;
    const size_t OBJ_SZ = (size_t)BB * TT * NN * 7;
    float4* rel4    = (float4*)out;
    float*  out_obj = out + REL_SZ;
    float4* recv4   = (float4*)(out + REL_SZ + OBJ_SZ);
    float4* send4   = (float4*)(out + REL_SZ + OBJ_SZ + REL_SZ);

    // ---- obj_data: 140 consecutive floats per bt, coalesced scalar writes ----
    if (tid < NN * 7) {
        const int n = tid / 7;
        const int c = tid - n * 7;
        float v;
        if (c < 2) {
            const float ang = s_state[n * 8 + 2];
            const float a   = (c == 0) ? ang : (ang + HALF_PI);
            v = cosf(a) * s_state[n * 8 + 3] + sinf(a) * s_state[n * 8 + 4];
        } else if (c == 2) {
            v = s_state[n * 8 + 5];
        } else {
            v = s_shape[n * 4 + (c - 3)];
        }
        out_obj[(size_t)bt * NN * 7 + tid] = v;
    }

    // ---- phase 1: compute each rel row ONCE into LDS (380 rows) ----
    for (int r = tid; r < NRR; r += 256) {
        const int i = r / 19;
        const int l = r - i * 19;
        const int j = (l < i) ? l : (l + 1);

        const float* si = &s_state[i * 8];
        const float* sj = &s_state[j * 8];

        const float dx = si[0] - sj[0];
        const float dy = si[1] - sj[1];
        const float d  = sqrtf(dx * dx + dy * dy);
        const float mask = (d < THRESH && d > 0.0f) ? 1.0f : 0.0f;

        const float dpx   = mask * (sj[0] - si[0]);
        const float dpy   = mask * (sj[1] - si[1]);
        const float adiff = mask * (sj[2] - si[2]);
        const float dvx   = mask * (sj[3] - si[3]);
        const float dvy   = mask * (sj[4] - si[4]);
        const float adv   = mask * (sj[5] - si[5]);
        const float cx    = mask * sj[6];
        const float cy    = mask * sj[7];

        const float rang = mask * si[2];
        const float c1 = cosf(rang),           s1 = sinf(rang);
        const float c2 = cosf(rang + HALF_PI), s2 = sinf(rang + HALF_PI);

        const float* ri = relinfo + ((size_t)bt * NRR + r) * 3;

        float4 w0, w1, w2, w3, w4;
        w0.x = ri[0]; w0.y = ri[1]; w0.z = ri[2];
        w0.w = c1 * dpx + s1 * dpy;
        w1.x = c2 * dpx + s2 * dpy;
        w1.y = c1 * dvx + s1 * dvy;
        w1.z = c2 * dvx + s2 * dvy;
        w1.w = c1 * cx  + s1 * cy;
        w2.x = c2 * cx  + s2 * cy;
        w2.y = sinf(2.0f * adiff);
        w2.z = cosf(2.0f * adiff);   // == 1 when masked out, as in reference
        w2.w = adv;
        w3.x = mask * s_shape[i * 4 + 0];
        w3.y = mask * s_shape[i * 4 + 1];
        w3.z = mask * s_shape[i * 4 + 2];
        w3.w = mask * s_shape[i * 4 + 3];
        w4.x = mask * s_shape[j * 4 + 0];
        w4.y = mask * s_shape[j * 4 + 1];
        w4.z = mask * s_shape[j * 4 + 2];
        w4.w = mask * s_shape[j * 4 + 3];

        float4* row = &s_row4[r * 5];
        row[0] = w0; row[1] = w1; row[2] = w2; row[3] = w3; row[4] = w4;
        s_mask[r] = mask;
        s_ij[r]   = i | (j << 8);
    }
    __syncthreads();

    // ---- phase 2: branch-free coalesced blast of all three big regions ----
    for (int idx = tid; idx < NRR * 5; idx += 256) {
        const int r = idx / 5;
        const int q = idx - r * 5;

        const float4 w  = s_row4[idx];       // linear ds_read_b128, conflict-free
        const float  m  = s_mask[r];
        const int    ij = s_ij[r];
        const int    i  = ij & 255;
        const int    j  = ij >> 8;
        const int    qb = q * 4;

        float4 rv, sv;
        rv.x = (i == qb + 0) ? m : 0.0f;
        rv.y = (i == qb + 1) ? m : 0.0f;
        rv.z = (i == qb + 2) ? m : 0.0f;
        rv.w = (i == qb + 3) ? m : 0.0f;
        sv.x = (j == qb + 0) ? m : 0.0f;
        sv.y = (j == qb + 1) ? m : 0.0f;
        sv.z = (j == qb + 2) ? m : 0.0f;
        sv.w = (j == qb + 3) ? m : 0.0f;

        const size_t o = (size_t)bt * (NRR * 5) + idx;
        rel4[o]  = w;
        recv4[o] = rv;
        send4[o] = sv;
    }
}

extern "C" void kernel_launch(void* const* d_in, const int* in_sizes, int n_in,
                              void* d_out, int out_size, void* d_ws, size_t ws_size,
                              hipStream_t stream) {
    const float* state = (const float*)d_in[0];
    const float* shp   = (const float*)d_in[1];
    const float* rel   = (const float*)d_in[2];
    float* out = (float*)d_out;
    gp_kernel<<<dim3(BB * TT), dim3(256), 0, stream>>>(state, shp, rel, out);
}